// Round 2
// baseline (8446.267 us; speedup 1.0000x reference)
//
#include <hip/hip_runtime.h>
#include <hip/hip_bf16.h>

#define HH 128
#define NNODES 1024
#define NB 8
#define KNBR 30
#define NV 21
#define NHALF 15
#define LEPS 1e-5f

typedef __hip_bfloat16 bf16;

__device__ __forceinline__ float b2f(bf16 v) { return __bfloat162float(v); }

// block = 128 threads (2 waves). Sum v over all 128 threads.
__device__ __forceinline__ float block_sum128(float v, float* scr) {
#pragma unroll
  for (int m = 32; m >= 1; m >>= 1) v += __shfl_xor(v, m, 64);
  __syncthreads();                       // protect scr from previous use
  if ((threadIdx.x & 63) == 0) scr[threadIdx.x >> 6] = v;
  __syncthreads();
  return scr[0] + scr[1];
}

// ---------------- h_V = V @ Wv + bv ;  h_S = Ws_emb[S] ----------------
__global__ __launch_bounds__(128) void k_init(
    const float* __restrict__ V, const float* __restrict__ Wv, const float* __restrict__ bv,
    const int* __restrict__ S, const float* __restrict__ Wse,
    float* __restrict__ hV, float* __restrict__ hS)
{
  const int r = blockIdx.x;
  const int j = threadIdx.x;
  __shared__ alignas(16) float sx[HH];
  sx[j] = V[(size_t)r * HH + j];
  __syncthreads();
  float acc = 0.f;
  for (int i = 0; i < HH; i += 4) {
    const float4 xv = *(const float4*)&sx[i];
    acc += xv.x * Wv[(i + 0) * HH + j];
    acc += xv.y * Wv[(i + 1) * HH + j];
    acc += xv.z * Wv[(i + 2) * HH + j];
    acc += xv.w * Wv[(i + 3) * HH + j];
  }
  hV[(size_t)r * HH + j] = acc + bv[j];
  hS[(size_t)r * HH + j] = Wse[(size_t)S[r] * HH + j];
}

// ---------------- h_E = E @ We + be (stored bf16 in ws) ----------------
__global__ __launch_bounds__(128) void k_edge_embed(
    const float* __restrict__ E, const float* __restrict__ We, const float* __restrict__ be,
    bf16* __restrict__ hE)
{
  const int r = blockIdx.x;   // node index b*N+n
  const int j = threadIdx.x;
  __shared__ alignas(16) float X[KNBR][HH];
  for (int k = 0; k < KNBR; ++k) X[k][j] = E[((size_t)r * KNBR + k) * HH + j];
  __syncthreads();
  float acc[KNBR];
#pragma unroll
  for (int k = 0; k < KNBR; ++k) acc[k] = 0.f;
  for (int i = 0; i < HH; i += 4) {
    const float w0 = We[(i + 0) * HH + j];
    const float w1 = We[(i + 1) * HH + j];
    const float w2 = We[(i + 2) * HH + j];
    const float w3 = We[(i + 3) * HH + j];
#pragma unroll
    for (int k = 0; k < KNBR; ++k) {
      const float4 xv = *(const float4*)&X[k][i];
      acc[k] += xv.x * w0 + xv.y * w1 + xv.z * w2 + xv.w * w3;
    }
  }
  const float bej = be[j];
  for (int k = 0; k < KNBR; ++k)
    hE[((size_t)r * KNBR + k) * HH + j] = __float2bfloat16(acc[k] + bej);
}

// ---------------- one MPNN layer (enc: DEC=0, dec: DEC=1) ----------------
// block = 128 threads = one node; fuses gather/concat + 3-GEMM edge MLP +
// masked K-sum + LN1 + FF + LN2 + mask_V.
template <int DEC>
__global__ __launch_bounds__(128) void k_mpnn(
    const float* __restrict__ hV_in, float* __restrict__ hV_out,
    const float* __restrict__ hV_enc, const float* __restrict__ hS,
    const bf16* __restrict__ hE,
    const int* __restrict__ E_idx, const float* __restrict__ mask,
    const float* __restrict__ W1, const float* __restrict__ b1,
    const float* __restrict__ W2, const float* __restrict__ b2,
    const float* __restrict__ W3, const float* __restrict__ b3,
    const float* __restrict__ Win, const float* __restrict__ bin,
    const float* __restrict__ Wff, const float* __restrict__ bff,
    const float* __restrict__ g1, const float* __restrict__ bt1,
    const float* __restrict__ g2, const float* __restrict__ bt2)
{
  constexpr int IN = DEC ? 3 * HH : 2 * HH;  // X width (excludes self block)
  const int r = blockIdx.x;
  const int b = r / NNODES, n = r % NNODES;
  const int j = threadIdx.x;

  __shared__ alignas(16) float X[NHALF][IN];
  __shared__ alignas(16) float Y1[NHALF][HH];
  __shared__ alignas(16) float Y2[NHALF][HH];
  __shared__ alignas(16) float hVs[HH];
  __shared__ alignas(16) float h1s[HH];
  __shared__ alignas(16) float us[4 * HH];
  __shared__ float scr[2];
  __shared__ int eidx[KNBR];
  __shared__ float watt[KNBR];
  __shared__ float wbw[KNBR], wfw[KNBR];

  hVs[j] = hV_in[(size_t)r * HH + j];
  const float m1 = mask[r];
  if (j < KNBR) {
    const int idx = E_idx[(size_t)r * KNBR + j];
    eidx[j] = idx;
    if (DEC) {
      const float ar = (idx < n) ? 1.f : 0.f;
      wbw[j] = m1 * ar;
      wfw[j] = m1 - m1 * ar;
      watt[j] = 1.f;
    } else {
      watt[j] = m1 * mask[b * NNODES + idx];
    }
  }
  __syncthreads();

  // self contribution: hV_self @ W1[0:128,:] + b1  (shared by all 30 edges)
  float sd = b1[j];
  for (int i = 0; i < HH; i += 4) {
    const float4 xv = *(const float4*)&hVs[i];
    sd += xv.x * W1[(i + 0) * HH + j];
    sd += xv.y * W1[(i + 1) * HH + j];
    sd += xv.z * W1[(i + 2) * HH + j];
    sd += xv.w * W1[(i + 3) * HH + j];
  }

  const float* W1r = W1 + HH * HH;  // rows 128..128+IN
  float dh = 0.f;

  for (int half = 0; half < 2; ++half) {
    const int k0 = half * NHALF;
    // ---- build X (gather + concat + decoder fw/bw blend) ----
    for (int k = 0; k < NHALF; ++k) {
      const int e = k0 + k;
      const int nb = eidx[e];
      const bf16* hErow = hE + ((size_t)r * KNBR + e) * HH;
      if (DEC) {
        const float bw = wbw[e], fw = wfw[e];
        X[k][j] = m1 * b2f(hErow[j]);
        X[k][HH + j] = bw * hS[((size_t)b * NNODES + nb) * HH + j];
        X[k][2 * HH + j] = bw * hV_in[((size_t)b * NNODES + nb) * HH + j] +
                           fw * hV_enc[((size_t)b * NNODES + nb) * HH + j];
      } else {
        X[k][j] = b2f(hErow[j]);
        X[k][HH + j] = hV_in[((size_t)b * NNODES + nb) * HH + j];
      }
    }
    __syncthreads();

    // ---- y1 = relu(x @ W1 + b1) ----
    float acc[NHALF];
#pragma unroll
    for (int k = 0; k < NHALF; ++k) acc[k] = sd;
    for (int i = 0; i < IN; i += 4) {
      const float w0 = W1r[(i + 0) * HH + j];
      const float w1 = W1r[(i + 1) * HH + j];
      const float w2 = W1r[(i + 2) * HH + j];
      const float w3 = W1r[(i + 3) * HH + j];
#pragma unroll
      for (int k = 0; k < NHALF; ++k) {
        const float4 xv = *(const float4*)&X[k][i];
        acc[k] += xv.x * w0 + xv.y * w1 + xv.z * w2 + xv.w * w3;
      }
    }
#pragma unroll
    for (int k = 0; k < NHALF; ++k) Y1[k][j] = fmaxf(acc[k], 0.f);
    __syncthreads();

    // ---- y2 = relu(y1 @ W2 + b2) ----
    const float b2j = b2[j];
#pragma unroll
    for (int k = 0; k < NHALF; ++k) acc[k] = b2j;
    for (int i = 0; i < HH; i += 4) {
      const float w0 = W2[(i + 0) * HH + j];
      const float w1 = W2[(i + 1) * HH + j];
      const float w2 = W2[(i + 2) * HH + j];
      const float w3 = W2[(i + 3) * HH + j];
#pragma unroll
      for (int k = 0; k < NHALF; ++k) {
        const float4 xv = *(const float4*)&Y1[k][i];
        acc[k] += xv.x * w0 + xv.y * w1 + xv.z * w2 + xv.w * w3;
      }
    }
#pragma unroll
    for (int k = 0; k < NHALF; ++k) Y2[k][j] = fmaxf(acc[k], 0.f);
    __syncthreads();

    // ---- y3 = y2 @ W3 + b3; masked sum over k ----
    const float b3j = b3[j];
#pragma unroll
    for (int k = 0; k < NHALF; ++k) acc[k] = b3j;
    for (int i = 0; i < HH; i += 4) {
      const float w0 = W3[(i + 0) * HH + j];
      const float w1 = W3[(i + 1) * HH + j];
      const float w2 = W3[(i + 2) * HH + j];
      const float w3 = W3[(i + 3) * HH + j];
#pragma unroll
      for (int k = 0; k < NHALF; ++k) {
        const float4 xv = *(const float4*)&Y2[k][i];
        acc[k] += xv.x * w0 + xv.y * w1 + xv.z * w2 + xv.w * w3;
      }
    }
#pragma unroll
    for (int k = 0; k < NHALF; ++k) dh += acc[k] * watt[k0 + k];
    __syncthreads();  // before next half overwrites X/Y1/Y2
  }

  // ---- node update: LN1, FF, LN2, mask_V ----
  const float hv = hVs[j] + dh * (1.0f / 30.0f);
  const float mu = block_sum128(hv, scr) * (1.0f / HH);
  const float dv = hv - mu;
  const float var = block_sum128(dv * dv, scr) * (1.0f / HH);
  const float h1 = g1[j] * dv * rsqrtf(var + LEPS) + bt1[j];

  h1s[j] = h1;
  __syncthreads();

#pragma unroll
  for (int t = 0; t < 4; ++t) {
    const int jj = j + t * HH;
    float a = bin[jj];
    for (int i = 0; i < HH; i += 4) {
      const float4 xv = *(const float4*)&h1s[i];
      a += xv.x * Win[(i + 0) * 4 * HH + jj];
      a += xv.y * Win[(i + 1) * 4 * HH + jj];
      a += xv.z * Win[(i + 2) * 4 * HH + jj];
      a += xv.w * Win[(i + 3) * 4 * HH + jj];
    }
    us[jj] = fmaxf(a, 0.f);
  }
  __syncthreads();

  float f = bff[j];
  for (int i = 0; i < 4 * HH; i += 4) {
    const float4 uv = *(const float4*)&us[i];
    f += uv.x * Wff[(i + 0) * HH + j];
    f += uv.y * Wff[(i + 1) * HH + j];
    f += uv.z * Wff[(i + 2) * HH + j];
    f += uv.w * Wff[(i + 3) * HH + j];
  }

  const float hv2 = h1 + f;
  const float mu2 = block_sum128(hv2, scr) * (1.0f / HH);
  const float d2 = hv2 - mu2;
  const float var2 = block_sum128(d2 * d2, scr) * (1.0f / HH);
  const float outv = (g2[j] * d2 * rsqrtf(var2 + LEPS) + bt2[j]) * m1;
  hV_out[(size_t)r * HH + j] = outv;
}

// ---------------- logits + log_softmax ----------------
__global__ __launch_bounds__(64) void k_out(
    const float* __restrict__ hV, const float* __restrict__ Wout,
    const float* __restrict__ bout, float* __restrict__ out)
{
  const int r = blockIdx.x;
  const int lane = threadIdx.x;
  __shared__ alignas(16) float sx[HH];
  sx[lane] = hV[(size_t)r * HH + lane];
  sx[lane + 64] = hV[(size_t)r * HH + lane + 64];
  __syncthreads();
  float logit = -1e30f;
  if (lane < NV) {
    float acc = bout[lane];
    for (int i = 0; i < HH; ++i) acc += sx[i] * Wout[i * NV + lane];
    logit = acc;
  }
  float mx = logit;
#pragma unroll
  for (int m = 32; m >= 1; m >>= 1) mx = fmaxf(mx, __shfl_xor(mx, m, 64));
  float e = (lane < NV) ? expf(logit - mx) : 0.f;
  float s = e;
#pragma unroll
  for (int m = 32; m >= 1; m >>= 1) s += __shfl_xor(s, m, 64);
  if (lane < NV) out[(size_t)r * NV + lane] = logit - mx - logf(s);
}

// ---------------- launcher ----------------
extern "C" void kernel_launch(void* const* d_in, const int* in_sizes, int n_in,
                              void* d_out, int out_size, void* d_ws, size_t ws_size,
                              hipStream_t stream)
{
  const int* S = (const int*)d_in[0];
  const float* V = (const float*)d_in[1];
  const float* E = (const float*)d_in[2];
  const int* E_idx = (const int*)d_in[3];
  const float* mask = (const float*)d_in[4];
  const float* Wv = (const float*)d_in[5];
  const float* bv = (const float*)d_in[6];
  const float* We = (const float*)d_in[7];
  const float* be = (const float*)d_in[8];
  const float* Wse = (const float*)d_in[9];
  const float* Wout = (const float*)d_in[10];
  const float* bout = (const float*)d_in[11];
  const float* eW[14];
  const float* dW[14];
  for (int i = 0; i < 14; ++i) eW[i] = (const float*)d_in[12 + i];
  for (int i = 0; i < 14; ++i) dW[i] = (const float*)d_in[26 + i];

  // ws layout (bytes):
  //   hE  bf16 : 245760*128*2 = 62,914,560
  //   hVa f32  : 4 MiB @ 62,914,560
  //   hVb f32  : 4 MiB @ 67,108,864
  //   hVc f32  : 4 MiB @ 71,303,168
  //   hS  f32  : 4 MiB @ 75,497,472        total ~79.7 MB
  char* w = (char*)d_ws;
  bf16* hE = (bf16*)w;
  float* hVa = (float*)(w + 62914560u);
  float* hVb = (float*)(w + 67108864u);
  float* hVc = (float*)(w + 71303168u);
  float* hS = (float*)(w + 75497472u);

  const int R = NB * NNODES;  // 8192

  k_init<<<R, 128, 0, stream>>>(V, Wv, bv, S, Wse, hVa, hS);
  k_edge_embed<<<R, 128, 0, stream>>>(E, We, be, hE);

  // per-layer weight pointer offsets
#define ENCA(l)                                                                      \
  eW[0] + (l) * 384 * HH, eW[1] + (l) * HH, eW[2] + (l) * HH * HH, eW[3] + (l) * HH, \
  eW[4] + (l) * HH * HH, eW[5] + (l) * HH, eW[6] + (l) * HH * 512, eW[7] + (l) * 512,\
  eW[8] + (l) * 512 * HH, eW[9] + (l) * HH, eW[10] + (l) * HH, eW[11] + (l) * HH,    \
  eW[12] + (l) * HH, eW[13] + (l) * HH
#define DECA(l)                                                                      \
  dW[0] + (l) * 512 * HH, dW[1] + (l) * HH, dW[2] + (l) * HH * HH, dW[3] + (l) * HH, \
  dW[4] + (l) * HH * HH, dW[5] + (l) * HH, dW[6] + (l) * HH * 512, dW[7] + (l) * 512,\
  dW[8] + (l) * 512 * HH, dW[9] + (l) * HH, dW[10] + (l) * HH, dW[11] + (l) * HH,    \
  dW[12] + (l) * HH, dW[13] + (l) * HH

  // encoder: a->b->a->b ; hV_enc ends in hVb
  k_mpnn<0><<<R, 128, 0, stream>>>(hVa, hVb, nullptr, nullptr, hE, E_idx, mask, ENCA(0));
  k_mpnn<0><<<R, 128, 0, stream>>>(hVb, hVa, nullptr, nullptr, hE, E_idx, mask, ENCA(1));
  k_mpnn<0><<<R, 128, 0, stream>>>(hVa, hVb, nullptr, nullptr, hE, E_idx, mask, ENCA(2));

  // decoder: b->a->c->a (hVb stays live as hV_enc)
  k_mpnn<1><<<R, 128, 0, stream>>>(hVb, hVa, hVb, hS, hE, E_idx, mask, DECA(0));
  k_mpnn<1><<<R, 128, 0, stream>>>(hVa, hVc, hVb, hS, hE, E_idx, mask, DECA(1));
  k_mpnn<1><<<R, 128, 0, stream>>>(hVc, hVa, hVb, hS, hE, E_idx, mask, DECA(2));

  k_out<<<R, 64, 0, stream>>>(hVa, Wout, bout, (float*)d_out);

#undef ENCA
#undef DECA
  (void)in_sizes; (void)n_in; (void)out_size; (void)ws_size;
}

// Round 3
// 959.312 us; speedup vs baseline: 8.8045x; 8.8045x over previous
//
#include <hip/hip_runtime.h>
#include <hip/hip_bf16.h>

#define HH 128
#define NN 1024
#define KNBR 30
#define NV 21
#define LEPS 1e-5f

typedef unsigned short ushort_t;
typedef __attribute__((ext_vector_type(8))) short short8;
typedef __attribute__((ext_vector_type(4))) float f32x4;

__device__ __forceinline__ ushort_t f2us(float f) {
  __hip_bfloat16 h = __float2bfloat16(f);
  return __builtin_bit_cast(unsigned short, h);
}
__device__ __forceinline__ float us2f(ushort_t u) {
  __hip_bfloat16 h = __builtin_bit_cast(__hip_bfloat16, u);
  return __bfloat162float(h);
}

// XOR-swizzled LDS helpers (row-major, rowB bytes/row, swizzle within 128B)
__device__ __forceinline__ void sw_store8(ushort_t* base, int row, int rowB, int colByte, short8 v) {
  int byte = row * rowB + colByte;
  byte ^= (row & 7) << 4;
  *(short8*)((char*)base + byte) = v;
}
__device__ __forceinline__ short8 sw_load8(const ushort_t* base, int row, int rowB, int colByte) {
  int byte = row * rowB + colByte;
  byte ^= (row & 7) << 4;
  return *(const short8*)((const char*)base + byte);
}
__device__ __forceinline__ void sw_store1(ushort_t* base, int row, int rowB, int col, ushort_t v) {
  int byte = row * rowB + col * 2;
  byte ^= (row & 7) << 4;
  *(ushort_t*)((char*)base + byte) = v;
}

// ---------------- weight prep: f32 [K][N] row-major -> bf16 fragment-linear ----
// frag idx: ((k>>5)*NT + (c>>4))*512 + (((k&31)>>3)*16 + (c&15))*8 + (k&7)
__global__ __launch_bounds__(256) void k_prep(const float* __restrict__ src,
                                              ushort_t* __restrict__ dst,
                                              int total, int nshift) {
  const int e = blockIdx.x * 256 + threadIdx.x;
  if (e >= total) return;
  const int k = e >> nshift;
  const int c = e & ((1 << nshift) - 1);
  const int NT = 1 << (nshift - 4);
  const int idx = ((k >> 5) * NT + (c >> 4)) * 512 + (((k & 31) >> 3) * 16 + (c & 15)) * 8 + (k & 7);
  dst[idx] = f2us(src[e]);
}

// ---------------- h_V = V @ Wv + bv ; h_S = Ws_emb[S] (bf16) ----------------
__global__ __launch_bounds__(128) void k_init(
    const float* __restrict__ V, const float* __restrict__ Wv, const float* __restrict__ bv,
    const int* __restrict__ S, const float* __restrict__ Wse,
    float* __restrict__ hV, ushort_t* __restrict__ hS)
{
  const int r = blockIdx.x;
  const int j = threadIdx.x;
  __shared__ alignas(16) float sx[HH];
  sx[j] = V[(size_t)r * HH + j];
  __syncthreads();
  float acc = 0.f;
  for (int i = 0; i < HH; i += 4) {
    const float4 xv = *(const float4*)&sx[i];
    acc += xv.x * Wv[(i + 0) * HH + j];
    acc += xv.y * Wv[(i + 1) * HH + j];
    acc += xv.z * Wv[(i + 2) * HH + j];
    acc += xv.w * Wv[(i + 3) * HH + j];
  }
  hV[(size_t)r * HH + j] = acc + bv[j];
  hS[(size_t)r * HH + j] = f2us(Wse[(size_t)S[r] * HH + j]);
}

// ---------------- h_E = E @ We + be (stored bf16 in ws) ----------------
__global__ __launch_bounds__(128) void k_edge_embed(
    const float* __restrict__ E, const float* __restrict__ We, const float* __restrict__ be,
    ushort_t* __restrict__ hE)
{
  const int r = blockIdx.x;
  const int j = threadIdx.x;
  __shared__ alignas(16) float X[KNBR][HH];
  for (int k = 0; k < KNBR; ++k) X[k][j] = E[((size_t)r * KNBR + k) * HH + j];
  __syncthreads();
  float acc[KNBR];
#pragma unroll
  for (int k = 0; k < KNBR; ++k) acc[k] = 0.f;
  for (int i = 0; i < HH; i += 4) {
    const float w0 = We[(i + 0) * HH + j];
    const float w1 = We[(i + 1) * HH + j];
    const float w2 = We[(i + 2) * HH + j];
    const float w3 = We[(i + 3) * HH + j];
#pragma unroll
    for (int k = 0; k < KNBR; ++k) {
      const float4 xv = *(const float4*)&X[k][i];
      acc[k] += xv.x * w0 + xv.y * w1 + xv.z * w2 + xv.w * w3;
    }
  }
  const float bej = be[j];
  for (int k = 0; k < KNBR; ++k)
    hE[((size_t)r * KNBR + k) * HH + j] = f2us(acc[k] + bej);
}

// ---------------- MFMA message kernel: 4 nodes/block, M=128 ----------------
// GEMM1: X[128 x INF] @ W1[INF x 128]; GEMM2/3: [128x128]@[128x128]
// then masked k-sum + LN1 -> h1 (bf16)
template <int DEC>
__global__ __launch_bounds__(256) void k_msg(
    const float* __restrict__ hV_in, const float* __restrict__ hV_enc,
    const ushort_t* __restrict__ hS, const ushort_t* __restrict__ hE,
    const ushort_t* __restrict__ W1f, const ushort_t* __restrict__ W2f,
    const ushort_t* __restrict__ W3f,
    const float* __restrict__ b1, const float* __restrict__ b2,
    const float* __restrict__ b3,
    const float* __restrict__ g1, const float* __restrict__ bt1,
    const int* __restrict__ E_idx, const float* __restrict__ mask,
    ushort_t* __restrict__ h1out)
{
  constexpr int INF = DEC ? 4 * HH : 3 * HH;  // full K of GEMM1 (incl self block)
  constexpr int SLABS = INF / 64;
  const int t = threadIdx.x;
  const int wid = t >> 6, lane = t & 63;
  const int wm = wid >> 1, wn = wid & 1;  // 2x2 wave grid; wave tile 64x64
  const int node0 = blockIdx.x * 4;
  const int bb = node0 >> 10;
  const int np0 = node0 & (NN - 1);

  __shared__ alignas(16) ushort_t Xs[128 * 64];    // 16KB, rowB=128
  __shared__ alignas(16) ushort_t Ys[128 * 128];   // 32KB, rowB=256 (Y1 then Y2)
  __shared__ float dhs[4][HH];
  __shared__ int s_nb[128];
  __shared__ float s_watt[128];
  __shared__ float s_bw[128];
  __shared__ float s_fw[128];
  __shared__ float s_m1[4];

  // ---- meta ----
  if (t < 128) {
    const int g = t >> 5, e = t & 31;
    const int r = node0 + g;
    const float m1 = mask[r];
    if (e == 0) s_m1[g] = m1;
    int nb = 0;
    float watt = 0.f, bw = 0.f, fw = 0.f;
    if (e < KNBR) {
      nb = E_idx[(size_t)r * KNBR + e];
      if (DEC) {
        const float ar = (nb < np0 + g) ? 1.f : 0.f;
        bw = m1 * ar;
        fw = m1 - bw;
        watt = 1.f;
      } else {
        watt = m1 * mask[bb * NN + nb];
      }
    }
    s_nb[t] = nb; s_watt[t] = watt; s_bw[t] = bw; s_fw[t] = fw;
  }
  __syncthreads();

  // ---- GEMM1 with slab-staged X ----
  f32x4 acc[4][4];
#pragma unroll
  for (int ni = 0; ni < 4; ++ni) {
    const float bv = b1[wn * 64 + ni * 16 + (lane & 15)];
#pragma unroll
    for (int mi = 0; mi < 4; ++mi) acc[mi][ni] = {bv, bv, bv, bv};
  }

  for (int s = 0; s < SLABS; ++s) {
    // stage X slab: thread t -> row m=t>>1, 32 cols at half*32
    {
      const int m = t >> 1, half = t & 1;
      const int g = m >> 5, e = m & 31;
      const int fc0 = s * 64 + half * 32;
      float vf[32];
      const bool valid = (e < KNBR);
      if (valid) {
        const int seg = fc0 >> 7;
        const int off = fc0 & 127;
        const int nb = s_nb[m];
        if (seg == 0) {  // self hV
          const float4* p = (const float4*)(hV_in + (size_t)(node0 + g) * HH + off);
#pragma unroll
          for (int i = 0; i < 8; ++i) {
            const float4 x = p[i];
            vf[i * 4 + 0] = x.x; vf[i * 4 + 1] = x.y; vf[i * 4 + 2] = x.z; vf[i * 4 + 3] = x.w;
          }
        } else if (seg == 1) {  // hE (x m1 for dec)
          const short8* p = (const short8*)(hE + ((size_t)(node0 + g) * KNBR + e) * HH + off);
          const float sc = DEC ? s_m1[g] : 1.f;
#pragma unroll
          for (int i = 0; i < 4; ++i) {
            const short8 x = p[i];
#pragma unroll
            for (int jj = 0; jj < 8; ++jj) vf[i * 8 + jj] = sc * us2f((ushort_t)x[jj]);
          }
        } else if (seg == 2) {
          if (DEC) {  // bw * hS[nb]
            const short8* p = (const short8*)(hS + (size_t)(bb * NN + nb) * HH + off);
            const float bw = s_bw[m];
#pragma unroll
            for (int i = 0; i < 4; ++i) {
              const short8 x = p[i];
#pragma unroll
              for (int jj = 0; jj < 8; ++jj) vf[i * 8 + jj] = bw * us2f((ushort_t)x[jj]);
            }
          } else {  // hV[nb]
            const float4* p = (const float4*)(hV_in + (size_t)(bb * NN + nb) * HH + off);
#pragma unroll
            for (int i = 0; i < 8; ++i) {
              const float4 x = p[i];
              vf[i * 4 + 0] = x.x; vf[i * 4 + 1] = x.y; vf[i * 4 + 2] = x.z; vf[i * 4 + 3] = x.w;
            }
          }
        } else {  // DEC seg3: bw*hV_in[nb] + fw*hV_enc[nb]
          const float4* p = (const float4*)(hV_in + (size_t)(bb * NN + nb) * HH + off);
          const float4* q = (const float4*)(hV_enc + (size_t)(bb * NN + nb) * HH + off);
          const float bw = s_bw[m], fw = s_fw[m];
#pragma unroll
          for (int i = 0; i < 8; ++i) {
            const float4 x = p[i];
            const float4 y = q[i];
            vf[i * 4 + 0] = bw * x.x + fw * y.x;
            vf[i * 4 + 1] = bw * x.y + fw * y.y;
            vf[i * 4 + 2] = bw * x.z + fw * y.z;
            vf[i * 4 + 3] = bw * x.w + fw * y.w;
          }
        }
      }
#pragma unroll
      for (int cg = 0; cg < 4; ++cg) {
        short8 w;
#pragma unroll
        for (int jj = 0; jj < 8; ++jj)
          w[jj] = valid ? (short)f2us(vf[cg * 8 + jj]) : (short)0;
        sw_store8(Xs, m, 128, half * 64 + cg * 16, w);
      }
    }
    __syncthreads();

#pragma unroll
    for (int kb = 0; kb < 2; ++kb) {
      const int kbg = s * 2 + kb;
      short8 A[4], Bf[4];
#pragma unroll
      for (int mi = 0; mi < 4; ++mi)
        A[mi] = sw_load8(Xs, wm * 64 + mi * 16 + (lane & 15), 128, kb * 64 + (lane >> 4) * 16);
#pragma unroll
      for (int ni = 0; ni < 4; ++ni)
        Bf[ni] = *(const short8*)&W1f[(((size_t)kbg * 8 + wn * 4 + ni) * 64 + lane) * 8];
#pragma unroll
      for (int mi = 0; mi < 4; ++mi)
#pragma unroll
        for (int ni = 0; ni < 4; ++ni)
          acc[mi][ni] = __builtin_amdgcn_mfma_f32_16x16x32_bf16(A[mi], Bf[ni], acc[mi][ni], 0, 0, 0);
    }
    __syncthreads();
  }

  // write Y1 = relu(.)
#pragma unroll
  for (int mi = 0; mi < 4; ++mi)
#pragma unroll
    for (int ni = 0; ni < 4; ++ni)
#pragma unroll
      for (int q = 0; q < 4; ++q) {
        const int row = wm * 64 + mi * 16 + (lane >> 4) * 4 + q;
        const int col = wn * 64 + ni * 16 + (lane & 15);
        sw_store1(Ys, row, 256, col, f2us(fmaxf(acc[mi][ni][q], 0.f)));
      }
  __syncthreads();

  // ---- GEMM2 ----
#pragma unroll
  for (int ni = 0; ni < 4; ++ni) {
    const float bv = b2[wn * 64 + ni * 16 + (lane & 15)];
#pragma unroll
    for (int mi = 0; mi < 4; ++mi) acc[mi][ni] = {bv, bv, bv, bv};
  }
#pragma unroll
  for (int kb = 0; kb < 4; ++kb) {
    short8 A[4], Bf[4];
#pragma unroll
    for (int mi = 0; mi < 4; ++mi)
      A[mi] = sw_load8(Ys, wm * 64 + mi * 16 + (lane & 15), 256, kb * 64 + (lane >> 4) * 16);
#pragma unroll
    for (int ni = 0; ni < 4; ++ni)
      Bf[ni] = *(const short8*)&W2f[(((size_t)kb * 8 + wn * 4 + ni) * 64 + lane) * 8];
#pragma unroll
    for (int mi = 0; mi < 4; ++mi)
#pragma unroll
      for (int ni = 0; ni < 4; ++ni)
        acc[mi][ni] = __builtin_amdgcn_mfma_f32_16x16x32_bf16(A[mi], Bf[ni], acc[mi][ni], 0, 0, 0);
  }
  __syncthreads();  // all waves done reading Y1
#pragma unroll
  for (int mi = 0; mi < 4; ++mi)
#pragma unroll
    for (int ni = 0; ni < 4; ++ni)
#pragma unroll
      for (int q = 0; q < 4; ++q) {
        const int row = wm * 64 + mi * 16 + (lane >> 4) * 4 + q;
        const int col = wn * 64 + ni * 16 + (lane & 15);
        sw_store1(Ys, row, 256, col, f2us(fmaxf(acc[mi][ni][q], 0.f)));
      }
  __syncthreads();

  // ---- GEMM3 ----
#pragma unroll
  for (int ni = 0; ni < 4; ++ni) {
    const float bv = b3[wn * 64 + ni * 16 + (lane & 15)];
#pragma unroll
    for (int mi = 0; mi < 4; ++mi) acc[mi][ni] = {bv, bv, bv, bv};
  }
#pragma unroll
  for (int kb = 0; kb < 4; ++kb) {
    short8 A[4], Bf[4];
#pragma unroll
    for (int mi = 0; mi < 4; ++mi)
      A[mi] = sw_load8(Ys, wm * 64 + mi * 16 + (lane & 15), 256, kb * 64 + (lane >> 4) * 16);
#pragma unroll
    for (int ni = 0; ni < 4; ++ni)
      Bf[ni] = *(const short8*)&W3f[(((size_t)kb * 8 + wn * 4 + ni) * 64 + lane) * 8];
#pragma unroll
    for (int mi = 0; mi < 4; ++mi)
#pragma unroll
      for (int ni = 0; ni < 4; ++ni)
        acc[mi][ni] = __builtin_amdgcn_mfma_f32_16x16x32_bf16(A[mi], Bf[ni], acc[mi][ni], 0, 0, 0);
  }

  // ---- masked sum over edge rows -> dh ----
  float wrow[4][4];
#pragma unroll
  for (int mi = 0; mi < 4; ++mi)
#pragma unroll
    for (int q = 0; q < 4; ++q)
      wrow[mi][q] = s_watt[wm * 64 + mi * 16 + (lane >> 4) * 4 + q];
#pragma unroll
  for (int ni = 0; ni < 4; ++ni) {
    float p0 = 0.f, p1 = 0.f;
#pragma unroll
    for (int q = 0; q < 4; ++q) {
      p0 += wrow[0][q] * acc[0][ni][q] + wrow[1][q] * acc[1][ni][q];
      p1 += wrow[2][q] * acc[2][ni][q] + wrow[3][q] * acc[3][ni][q];
    }
    p0 += __shfl_xor(p0, 16, 64); p0 += __shfl_xor(p0, 32, 64);
    p1 += __shfl_xor(p1, 16, 64); p1 += __shfl_xor(p1, 32, 64);
    if (lane < 16) {
      dhs[wm * 2 + 0][wn * 64 + ni * 16 + lane] = p0;
      dhs[wm * 2 + 1][wn * 64 + ni * 16 + lane] = p1;
    }
  }
  __syncthreads();

  // ---- LN1: wave wid handles node wid ----
  {
    const int r = node0 + wid;
    const float x0 = hV_in[(size_t)r * HH + lane] + dhs[wid][lane] * (1.f / 30.f);
    const float x1 = hV_in[(size_t)r * HH + lane + 64] + dhs[wid][lane + 64] * (1.f / 30.f);
    float sm = x0 + x1;
#pragma unroll
    for (int m = 32; m >= 1; m >>= 1) sm += __shfl_xor(sm, m, 64);
    const float mu = sm * (1.f / HH);
    const float d0 = x0 - mu, d1 = x1 - mu;
    float vv = d0 * d0 + d1 * d1;
#pragma unroll
    for (int m = 32; m >= 1; m >>= 1) vv += __shfl_xor(vv, m, 64);
    const float rs = rsqrtf(vv * (1.f / HH) + LEPS);
    h1out[(size_t)r * HH + lane] = f2us(g1[lane] * d0 * rs + bt1[lane]);
    h1out[(size_t)r * HH + lane + 64] = f2us(g1[lane + 64] * d1 * rs + bt1[lane + 64]);
  }
}

// ---------------- FF kernel: 64 rows/block; u=relu(h1@Win+bin); f=u@Wff+bff;
// h2=h1+f; LN2; x mask ----------------
__global__ __launch_bounds__(256) void k_ff(
    const ushort_t* __restrict__ h1, const ushort_t* __restrict__ Winf,
    const ushort_t* __restrict__ Wfff,
    const float* __restrict__ bin, const float* __restrict__ bff,
    const float* __restrict__ g2, const float* __restrict__ bt2,
    const float* __restrict__ mask, float* __restrict__ hV_out)
{
  const int t = threadIdx.x, wid = t >> 6, lane = t & 63;
  const int row0 = blockIdx.x * 64;
  __shared__ alignas(16) ushort_t As[64 * 128];   // 16KB rowB=256
  __shared__ alignas(16) ushort_t Us[64 * 512];   // 64KB rowB=1024; reused as f32 h2[64][128]

  {
    const int row = t >> 2, cq = t & 3;
    const short8* p = (const short8*)(h1 + (size_t)(row0 + row) * HH + cq * 32);
#pragma unroll
    for (int i = 0; i < 4; ++i) sw_store8(As, row, 256, cq * 64 + i * 16, p[i]);
  }
  __syncthreads();

  // GEMM A: wave covers cols wid*128..+127 of N=512
  f32x4 ua[4][8];
#pragma unroll
  for (int ni = 0; ni < 8; ++ni) {
    const float bv = bin[wid * 128 + ni * 16 + (lane & 15)];
#pragma unroll
    for (int mi = 0; mi < 4; ++mi) ua[mi][ni] = {bv, bv, bv, bv};
  }
#pragma unroll
  for (int kb = 0; kb < 4; ++kb) {
    short8 A[4], Bf[8];
#pragma unroll
    for (int mi = 0; mi < 4; ++mi)
      A[mi] = sw_load8(As, mi * 16 + (lane & 15), 256, kb * 64 + (lane >> 4) * 16);
#pragma unroll
    for (int ni = 0; ni < 8; ++ni)
      Bf[ni] = *(const short8*)&Winf[(((size_t)kb * 32 + wid * 8 + ni) * 64 + lane) * 8];
#pragma unroll
    for (int mi = 0; mi < 4; ++mi)
#pragma unroll
      for (int ni = 0; ni < 8; ++ni)
        ua[mi][ni] = __builtin_amdgcn_mfma_f32_16x16x32_bf16(A[mi], Bf[ni], ua[mi][ni], 0, 0, 0);
  }
#pragma unroll
  for (int mi = 0; mi < 4; ++mi)
#pragma unroll
    for (int ni = 0; ni < 8; ++ni)
#pragma unroll
      for (int q = 0; q < 4; ++q) {
        const int row = mi * 16 + (lane >> 4) * 4 + q;
        const int col = wid * 128 + ni * 16 + (lane & 15);
        sw_store1(Us, row, 1024, col, f2us(fmaxf(ua[mi][ni][q], 0.f)));
      }
  __syncthreads();

  // GEMM B: wave covers cols wid*32..+31 of N=128; K=512
  f32x4 fa[4][2];
#pragma unroll
  for (int ni = 0; ni < 2; ++ni) {
    const float bv = bff[wid * 32 + ni * 16 + (lane & 15)];
#pragma unroll
    for (int mi = 0; mi < 4; ++mi) fa[mi][ni] = {bv, bv, bv, bv};
  }
#pragma unroll
  for (int kb = 0; kb < 16; ++kb) {
    short8 A[4], Bf[2];
#pragma unroll
    for (int mi = 0; mi < 4; ++mi)
      A[mi] = sw_load8(Us, mi * 16 + (lane & 15), 1024, kb * 64 + (lane >> 4) * 16);
#pragma unroll
    for (int ni = 0; ni < 2; ++ni)
      Bf[ni] = *(const short8*)&Wfff[(((size_t)kb * 8 + wid * 2 + ni) * 64 + lane) * 8];
#pragma unroll
    for (int mi = 0; mi < 4; ++mi)
#pragma unroll
      for (int ni = 0; ni < 2; ++ni)
        fa[mi][ni] = __builtin_amdgcn_mfma_f32_16x16x32_bf16(A[mi], Bf[ni], fa[mi][ni], 0, 0, 0);
  }
  __syncthreads();  // all reads of Us done

  float* h2 = (float*)Us;
#pragma unroll
  for (int mi = 0; mi < 4; ++mi)
#pragma unroll
    for (int ni = 0; ni < 2; ++ni)
#pragma unroll
      for (int q = 0; q < 4; ++q) {
        const int row = mi * 16 + (lane >> 4) * 4 + q;
        const int col = wid * 32 + ni * 16 + (lane & 15);
        const float res = us2f(h1[(size_t)(row0 + row) * HH + col]);
        h2[row * HH + col] = res + fa[mi][ni][q];
      }
  __syncthreads();

  // LN2 + mask: 4 threads per row
  {
    const int row = t >> 2, quad = t & 3;
    float x[32];
    float sm = 0.f;
#pragma unroll
    for (int i = 0; i < 32; ++i) { x[i] = h2[row * HH + quad + i * 4]; sm += x[i]; }
    sm += __shfl_xor(sm, 1, 64); sm += __shfl_xor(sm, 2, 64);
    const float mu = sm * (1.f / HH);
    float vv = 0.f;
#pragma unroll
    for (int i = 0; i < 32; ++i) { const float d = x[i] - mu; vv += d * d; }
    vv += __shfl_xor(vv, 1, 64); vv += __shfl_xor(vv, 2, 64);
    const float rs = rsqrtf(vv * (1.f / HH) + LEPS);
    const float m1 = mask[row0 + row];
#pragma unroll
    for (int i = 0; i < 32; ++i) {
      const int col = quad + i * 4;
      hV_out[(size_t)(row0 + row) * HH + col] = (g2[col] * (x[i] - mu) * rs + bt2[col]) * m1;
    }
  }
}

// ---------------- logits + log_softmax ----------------
__global__ __launch_bounds__(64) void k_out(
    const float* __restrict__ hV, const float* __restrict__ Wout,
    const float* __restrict__ bout, float* __restrict__ out)
{
  const int r = blockIdx.x;
  const int lane = threadIdx.x;
  __shared__ alignas(16) float sx[HH];
  sx[lane] = hV[(size_t)r * HH + lane];
  sx[lane + 64] = hV[(size_t)r * HH + lane + 64];
  __syncthreads();
  float logit = -1e30f;
  if (lane < NV) {
    float acc = bout[lane];
    for (int i = 0; i < HH; ++i) acc += sx[i] * Wout[i * NV + lane];
    logit = acc;
  }
  float mx = logit;
#pragma unroll
  for (int m = 32; m >= 1; m >>= 1) mx = fmaxf(mx, __shfl_xor(mx, m, 64));
  float e = (lane < NV) ? expf(logit - mx) : 0.f;
  float s = e;
#pragma unroll
  for (int m = 32; m >= 1; m >>= 1) s += __shfl_xor(s, m, 64);
  if (lane < NV) out[(size_t)r * NV + lane] = logit - mx - logf(s);
}

// ---------------- launcher ----------------
extern "C" void kernel_launch(void* const* d_in, const int* in_sizes, int n_in,
                              void* d_out, int out_size, void* d_ws, size_t ws_size,
                              hipStream_t stream)
{
  const int* S = (const int*)d_in[0];
  const float* V = (const float*)d_in[1];
  const float* E = (const float*)d_in[2];
  const int* E_idx = (const int*)d_in[3];
  const float* mask = (const float*)d_in[4];
  const float* Wv = (const float*)d_in[5];
  const float* bv = (const float*)d_in[6];
  const float* We = (const float*)d_in[7];
  const float* be = (const float*)d_in[8];
  const float* Wse = (const float*)d_in[9];
  const float* Wout = (const float*)d_in[10];
  const float* bout = (const float*)d_in[11];
  const float* eW[14];
  const float* dW[14];
  for (int i = 0; i < 14; ++i) eW[i] = (const float*)d_in[12 + i];
  for (int i = 0; i < 14; ++i) dW[i] = (const float*)d_in[26 + i];

  // ws layout (bytes):
  //   hE  bf16 : 62,914,560 @ 0
  //   hVa f32  :  4,194,304 @ 62,914,560
  //   hVb f32  :  4,194,304 @ 67,108,864
  //   h1  bf16 :  2,097,152 @ 71,303,168
  //   hS  bf16 :  2,097,152 @ 73,400,320
  //   WP  bf16 :  2,654,208 @ 75,497,472   (end 78,151,680)
  char* w = (char*)d_ws;
  ushort_t* hE = (ushort_t*)w;
  float* hVa = (float*)(w + 62914560u);
  float* hVb = (float*)(w + 67108864u);
  ushort_t* h1 = (ushort_t*)(w + 71303168u);
  ushort_t* hS = (ushort_t*)(w + 73400320u);
  ushort_t* WP = (ushort_t*)(w + 75497472u);

  const int R = 8 * NN;  // 8192

  // ---- weight prep ----
  auto prep = [&](const float* src, ushort_t* dst, int K, int nshift) {
    const int total = K << nshift;
    k_prep<<<(total + 255) / 256, 256, 0, stream>>>(src, dst, total, nshift);
  };
  for (int l = 0; l < 3; ++l) {
    ushort_t* base = WP + l * 212992;
    prep(eW[0] + l * 384 * 128, base + 0,      384, 7);  // W1
    prep(eW[2] + l * 128 * 128, base + 49152,  128, 7);  // W2
    prep(eW[4] + l * 128 * 128, base + 65536,  128, 7);  // W3
    prep(eW[6] + l * 128 * 512, base + 81920,  128, 9);  // Win
    prep(eW[8] + l * 512 * 128, base + 147456, 512, 7);  // Wff
  }
  for (int l = 0; l < 3; ++l) {
    ushort_t* base = WP + 638976 + l * 229376;
    prep(dW[0] + l * 512 * 128, base + 0,      512, 7);
    prep(dW[2] + l * 128 * 128, base + 65536,  128, 7);
    prep(dW[4] + l * 128 * 128, base + 81920,  128, 7);
    prep(dW[6] + l * 128 * 512, base + 98304,  128, 9);
    prep(dW[8] + l * 512 * 128, base + 163840, 512, 7);
  }

  k_init<<<R, 128, 0, stream>>>(V, Wv, bv, S, Wse, hVa, hS);
  k_edge_embed<<<R, 128, 0, stream>>>(E, We, be, hE);

  // encoder (in-place on hVa: msg reads hVa fully before ff overwrites it)
  for (int l = 0; l < 3; ++l) {
    const ushort_t* base = WP + l * 212992;
    k_msg<0><<<2048, 256, 0, stream>>>(hVa, hVa, hS, hE,
        base, base + 49152, base + 65536,
        eW[1] + l * 128, eW[3] + l * 128, eW[5] + l * 128,
        eW[10] + l * 128, eW[11] + l * 128, E_idx, mask, h1);
    k_ff<<<128, 256, 0, stream>>>(h1, base + 81920, base + 147456,
        eW[7] + l * 512, eW[9] + l * 128, eW[12] + l * 128, eW[13] + l * 128,
        mask, hVa);
  }
  // decoder: hV_enc = hVa (preserved); state rotates into hVb
  for (int l = 0; l < 3; ++l) {
    const ushort_t* base = WP + 638976 + l * 229376;
    const float* hin = (l == 0) ? hVa : hVb;
    k_msg<1><<<2048, 256, 0, stream>>>(hin, hVa, hS, hE,
        base, base + 65536, base + 81920,
        dW[1] + l * 128, dW[3] + l * 128, dW[5] + l * 128,
        dW[10] + l * 128, dW[11] + l * 128, E_idx, mask, h1);
    k_ff<<<128, 256, 0, stream>>>(h1, base + 98304, base + 163840,
        dW[7] + l * 512, dW[9] + l * 128, dW[12] + l * 128, dW[13] + l * 128,
        mask, hVb);
  }

  k_out<<<R, 64, 0, stream>>>(hVb, Wout, bout, (float*)d_out);

  (void)in_sizes; (void)n_in; (void)out_size; (void)ws_size;
}

// Round 5
// 788.398 us; speedup vs baseline: 10.7132x; 1.2168x over previous
//
#include <hip/hip_runtime.h>
#include <hip/hip_bf16.h>

#define HH 128
#define NN 1024
#define KNBR 30
#define NV 21
#define LEPS 1e-5f

typedef unsigned short ushort_t;
typedef __attribute__((ext_vector_type(8))) short short8;
typedef __attribute__((ext_vector_type(4))) short shortv4;
typedef __attribute__((ext_vector_type(4))) float f32x4;

__device__ __forceinline__ ushort_t f2us(float f) {
  __hip_bfloat16 h = __float2bfloat16(f);
  return __builtin_bit_cast(unsigned short, h);
}
__device__ __forceinline__ float us2f(ushort_t u) {
  __hip_bfloat16 h = __builtin_bit_cast(__hip_bfloat16, u);
  return __bfloat162float(h);
}

// XOR-swizzled LDS helpers (row-major, rowB bytes/row, swizzle within 128B)
__device__ __forceinline__ void sw_store8(ushort_t* base, int row, int rowB, int colByte, short8 v) {
  int byte = row * rowB + colByte;
  byte ^= (row & 7) << 4;
  *(short8*)((char*)base + byte) = v;
}
__device__ __forceinline__ short8 sw_load8(const ushort_t* base, int row, int rowB, int colByte) {
  int byte = row * rowB + colByte;
  byte ^= (row & 7) << 4;
  return *(const short8*)((const char*)base + byte);
}
__device__ __forceinline__ void sw_store1(ushort_t* base, int row, int rowB, int col, ushort_t v) {
  int byte = row * rowB + col * 2;
  byte ^= (row & 7) << 4;
  *(ushort_t*)((char*)base + byte) = v;
}

// ---------------- merged weight prep: 32 tensors in one launch ----------------
// frag idx: ((k>>5)*NT + (c>>4))*512 + (((k&31)>>3)*16 + (c&15))*8 + (k&7)
struct PrepTab {
  const float* src[32];
  unsigned dstOff[32];
  int blk0[32];     // starting block of each tensor (each block = 256 elems)
  int nshift[32];
};

__global__ __launch_bounds__(256) void k_prep_all(PrepTab tab, ushort_t* __restrict__ dst) {
  const int bid = blockIdx.x;
  int ti = 0;
#pragma unroll 1
  for (int i = 1; i < 32; ++i)
    if (bid >= tab.blk0[i]) ti = i;
  const int nshift = tab.nshift[ti];
  const int e = (bid - tab.blk0[ti]) * 256 + threadIdx.x;
  const int k = e >> nshift;
  const int c = e & ((1 << nshift) - 1);
  const int NT = 1 << (nshift - 4);
  const int idx = ((k >> 5) * NT + (c >> 4)) * 512 + (((k & 31) >> 3) * 16 + (c & 15)) * 8 + (k & 7);
  dst[tab.dstOff[ti] + idx] = f2us(tab.src[ti][e]);
}

// ---------------- generic 128x128x128 MFMA GEMM over row tiles ----------------
// C[r][j] = sum_k A[r][k]*W[k][j] + b[j].  OUTBF16: bf16 out via LDS roundtrip
// (coalesced); else direct f32 stores.
template <int OUTBF16>
__global__ __launch_bounds__(256) void k_gemm128(
    const float* __restrict__ A, const ushort_t* __restrict__ Wf,
    const float* __restrict__ bias, void* __restrict__ out)
{
  const int t = threadIdx.x, wid = t >> 6, lane = t & 63;
  const int wm = wid >> 1, wn = wid & 1;
  const size_t row0 = (size_t)blockIdx.x * 128;
  __shared__ alignas(16) ushort_t Xs[128 * 128];  // 32KB, rowB=256

  // stage A tile (f32 -> bf16, swizzled): thread covers 64 floats = 8 x short8
  {
    const int row = t >> 1, half = t & 1;
    const float4* p = (const float4*)(A + (row0 + row) * HH + half * 64);
#pragma unroll
    for (int i = 0; i < 8; ++i) {
      short8 wv;
#pragma unroll
      for (int jj = 0; jj < 2; ++jj) {
        const float4 x = p[i * 2 + jj];
        wv[jj * 4 + 0] = (short)f2us(x.x);
        wv[jj * 4 + 1] = (short)f2us(x.y);
        wv[jj * 4 + 2] = (short)f2us(x.z);
        wv[jj * 4 + 3] = (short)f2us(x.w);
      }
      sw_store8(Xs, row, 256, half * 128 + i * 16, wv);
    }
  }
  __syncthreads();

  f32x4 acc[4][4];
#pragma unroll
  for (int ni = 0; ni < 4; ++ni) {
    const float bv = bias[wn * 64 + ni * 16 + (lane & 15)];
#pragma unroll
    for (int mi = 0; mi < 4; ++mi) acc[mi][ni] = {bv, bv, bv, bv};
  }
#pragma unroll
  for (int kb = 0; kb < 4; ++kb) {
    short8 Af[4], Bf[4];
#pragma unroll
    for (int mi = 0; mi < 4; ++mi)
      Af[mi] = sw_load8(Xs, wm * 64 + mi * 16 + (lane & 15), 256, kb * 64 + (lane >> 4) * 16);
#pragma unroll
    for (int ni = 0; ni < 4; ++ni)
      Bf[ni] = *(const short8*)&Wf[(((size_t)kb * 8 + wn * 4 + ni) * 64 + lane) * 8];
#pragma unroll
    for (int mi = 0; mi < 4; ++mi)
#pragma unroll
      for (int ni = 0; ni < 4; ++ni)
        acc[mi][ni] = __builtin_amdgcn_mfma_f32_16x16x32_bf16(Af[mi], Bf[ni], acc[mi][ni], 0, 0, 0);
  }

  if constexpr (OUTBF16) {
    __syncthreads();  // done reading Xs
#pragma unroll
    for (int mi = 0; mi < 4; ++mi)
#pragma unroll
      for (int ni = 0; ni < 4; ++ni)
#pragma unroll
        for (int q = 0; q < 4; ++q) {
          const int row = wm * 64 + mi * 16 + (lane >> 4) * 4 + q;
          const int col = wn * 64 + ni * 16 + (lane & 15);
          sw_store1(Xs, row, 256, col, f2us(acc[mi][ni][q]));
        }
    __syncthreads();
    {
      const int row = t >> 1, half = t & 1;
      ushort_t* o = (ushort_t*)out + (row0 + row) * HH + half * 64;
#pragma unroll
      for (int i = 0; i < 8; ++i)
        *(short8*)(o + i * 8) = sw_load8(Xs, row, 256, half * 128 + i * 16);
    }
  } else {
    float* of = (float*)out;
#pragma unroll
    for (int mi = 0; mi < 4; ++mi)
#pragma unroll
      for (int ni = 0; ni < 4; ++ni)
#pragma unroll
        for (int q = 0; q < 4; ++q) {
          const int row = wm * 64 + mi * 16 + (lane >> 4) * 4 + q;
          const int col = wn * 64 + ni * 16 + (lane & 15);
          of[(row0 + row) * HH + col] = acc[mi][ni][q];
        }
  }
}

// ---------------- h_S = Ws_emb[S] (bf16), vectorized gather ----------------
__global__ __launch_bounds__(256) void k_hs(
    const int* __restrict__ S, const float* __restrict__ Wse, ushort_t* __restrict__ hS)
{
  const int e = blockIdx.x * 256 + threadIdx.x;  // 4-elem groups, total 8192*32
  const int r = e >> 5, cq = e & 31;
  const float4 x = *(const float4*)(Wse + (size_t)S[r] * HH + cq * 4);
  shortv4 v;
  v[0] = (short)f2us(x.x); v[1] = (short)f2us(x.y);
  v[2] = (short)f2us(x.z); v[3] = (short)f2us(x.w);
  *(shortv4*)(hS + (size_t)r * HH + cq * 4) = v;
}

// ---------------- MFMA message kernel: 4 nodes/block, M=128 ----------------
template <int DEC>
__global__ __launch_bounds__(256) void k_msg(
    const float* __restrict__ hV_in, const float* __restrict__ hV_enc,
    const ushort_t* __restrict__ hS, const ushort_t* __restrict__ hE,
    const ushort_t* __restrict__ W1f, const ushort_t* __restrict__ W2f,
    const ushort_t* __restrict__ W3f,
    const float* __restrict__ b1, const float* __restrict__ b2,
    const float* __restrict__ b3,
    const float* __restrict__ g1, const float* __restrict__ bt1,
    const int* __restrict__ E_idx, const float* __restrict__ mask,
    ushort_t* __restrict__ h1out)
{
  constexpr int INF = DEC ? 4 * HH : 3 * HH;
  constexpr int SLABS = INF / 64;
  const int t = threadIdx.x;
  const int wid = t >> 6, lane = t & 63;
  const int wm = wid >> 1, wn = wid & 1;
  const int node0 = blockIdx.x * 4;
  const int bb = node0 >> 10;
  const int np0 = node0 & (NN - 1);

  __shared__ alignas(16) ushort_t Xs[128 * 64];
  __shared__ alignas(16) ushort_t Ys[128 * 128];
  __shared__ float dhs[4][HH];
  __shared__ int s_nb[128];
  __shared__ float s_watt[128];
  __shared__ float s_bw[128];
  __shared__ float s_fw[128];
  __shared__ float s_m1[4];

  if (t < 128) {
    const int g = t >> 5, e = t & 31;
    const int r = node0 + g;
    const float m1 = mask[r];
    if (e == 0) s_m1[g] = m1;
    int nb = 0;
    float watt = 0.f, bw = 0.f, fw = 0.f;
    if (e < KNBR) {
      nb = E_idx[(size_t)r * KNBR + e];
      if (DEC) {
        const float ar = (nb < np0 + g) ? 1.f : 0.f;
        bw = m1 * ar;
        fw = m1 - bw;
        watt = 1.f;
      } else {
        watt = m1 * mask[bb * NN + nb];
      }
    }
    s_nb[t] = nb; s_watt[t] = watt; s_bw[t] = bw; s_fw[t] = fw;
  }
  __syncthreads();

  f32x4 acc[4][4];
#pragma unroll
  for (int ni = 0; ni < 4; ++ni) {
    const float bv = b1[wn * 64 + ni * 16 + (lane & 15)];
#pragma unroll
    for (int mi = 0; mi < 4; ++mi) acc[mi][ni] = {bv, bv, bv, bv};
  }

  for (int s = 0; s < SLABS; ++s) {
    {
      const int m = t >> 1, half = t & 1;
      const int g = m >> 5, e = m & 31;
      const int fc0 = s * 64 + half * 32;
      float vf[32];
      const bool valid = (e < KNBR);
      if (valid) {
        const int seg = fc0 >> 7;
        const int off = fc0 & 127;
        const int nb = s_nb[m];
        if (seg == 0) {
          const float4* p = (const float4*)(hV_in + (size_t)(node0 + g) * HH + off);
#pragma unroll
          for (int i = 0; i < 8; ++i) {
            const float4 x = p[i];
            vf[i * 4 + 0] = x.x; vf[i * 4 + 1] = x.y; vf[i * 4 + 2] = x.z; vf[i * 4 + 3] = x.w;
          }
        } else if (seg == 1) {
          const short8* p = (const short8*)(hE + ((size_t)(node0 + g) * KNBR + e) * HH + off);
          const float sc = DEC ? s_m1[g] : 1.f;
#pragma unroll
          for (int i = 0; i < 4; ++i) {
            const short8 x = p[i];
#pragma unroll
            for (int jj = 0; jj < 8; ++jj) vf[i * 8 + jj] = sc * us2f((ushort_t)x[jj]);
          }
        } else if (seg == 2) {
          if (DEC) {
            const short8* p = (const short8*)(hS + (size_t)(bb * NN + nb) * HH + off);
            const float bw = s_bw[m];
#pragma unroll
            for (int i = 0; i < 4; ++i) {
              const short8 x = p[i];
#pragma unroll
              for (int jj = 0; jj < 8; ++jj) vf[i * 8 + jj] = bw * us2f((ushort_t)x[jj]);
            }
          } else {
            const float4* p = (const float4*)(hV_in + (size_t)(bb * NN + nb) * HH + off);
#pragma unroll
            for (int i = 0; i < 8; ++i) {
              const float4 x = p[i];
              vf[i * 4 + 0] = x.x; vf[i * 4 + 1] = x.y; vf[i * 4 + 2] = x.z; vf[i * 4 + 3] = x.w;
            }
          }
        } else {
          const float4* p = (const float4*)(hV_in + (size_t)(bb * NN + nb) * HH + off);
          const float4* q = (const float4*)(hV_enc + (size_t)(bb * NN + nb) * HH + off);
          const float bw = s_bw[m], fw = s_fw[m];
#pragma unroll
          for (int i = 0; i < 8; ++i) {
            const float4 x = p[i];
            const float4 y = q[i];
            vf[i * 4 + 0] = bw * x.x + fw * y.x;
            vf[i * 4 + 1] = bw * x.y + fw * y.y;
            vf[i * 4 + 2] = bw * x.z + fw * y.z;
            vf[i * 4 + 3] = bw * x.w + fw * y.w;
          }
        }
      }
#pragma unroll
      for (int cg = 0; cg < 4; ++cg) {
        short8 w;
#pragma unroll
        for (int jj = 0; jj < 8; ++jj)
          w[jj] = valid ? (short)f2us(vf[cg * 8 + jj]) : (short)0;
        sw_store8(Xs, m, 128, half * 64 + cg * 16, w);
      }
    }
    __syncthreads();

#pragma unroll
    for (int kb = 0; kb < 2; ++kb) {
      const int kbg = s * 2 + kb;
      short8 A[4], Bf[4];
#pragma unroll
      for (int mi = 0; mi < 4; ++mi)
        A[mi] = sw_load8(Xs, wm * 64 + mi * 16 + (lane & 15), 128, kb * 64 + (lane >> 4) * 16);
#pragma unroll
      for (int ni = 0; ni < 4; ++ni)
        Bf[ni] = *(const short8*)&W1f[(((size_t)kbg * 8 + wn * 4 + ni) * 64 + lane) * 8];
#pragma unroll
      for (int mi = 0; mi < 4; ++mi)
#pragma unroll
        for (int ni = 0; ni < 4; ++ni)
          acc[mi][ni] = __builtin_amdgcn_mfma_f32_16x16x32_bf16(A[mi], Bf[ni], acc[mi][ni], 0, 0, 0);
    }
    __syncthreads();
  }

#pragma unroll
  for (int mi = 0; mi < 4; ++mi)
#pragma unroll
    for (int ni = 0; ni < 4; ++ni)
#pragma unroll
      for (int q = 0; q < 4; ++q) {
        const int row = wm * 64 + mi * 16 + (lane >> 4) * 4 + q;
        const int col = wn * 64 + ni * 16 + (lane & 15);
        sw_store1(Ys, row, 256, col, f2us(fmaxf(acc[mi][ni][q], 0.f)));
      }
  __syncthreads();

#pragma unroll
  for (int ni = 0; ni < 4; ++ni) {
    const float bv = b2[wn * 64 + ni * 16 + (lane & 15)];
#pragma unroll
    for (int mi = 0; mi < 4; ++mi) acc[mi][ni] = {bv, bv, bv, bv};
  }
#pragma unroll
  for (int kb = 0; kb < 4; ++kb) {
    short8 A[4], Bf[4];
#pragma unroll
    for (int mi = 0; mi < 4; ++mi)
      A[mi] = sw_load8(Ys, wm * 64 + mi * 16 + (lane & 15), 256, kb * 64 + (lane >> 4) * 16);
#pragma unroll
    for (int ni = 0; ni < 4; ++ni)
      Bf[ni] = *(const short8*)&W2f[(((size_t)kb * 8 + wn * 4 + ni) * 64 + lane) * 8];
#pragma unroll
    for (int mi = 0; mi < 4; ++mi)
#pragma unroll
      for (int ni = 0; ni < 4; ++ni)
        acc[mi][ni] = __builtin_amdgcn_mfma_f32_16x16x32_bf16(A[mi], Bf[ni], acc[mi][ni], 0, 0, 0);
  }
  __syncthreads();
#pragma unroll
  for (int mi = 0; mi < 4; ++mi)
#pragma unroll
    for (int ni = 0; ni < 4; ++ni)
#pragma unroll
      for (int q = 0; q < 4; ++q) {
        const int row = wm * 64 + mi * 16 + (lane >> 4) * 4 + q;
        const int col = wn * 64 + ni * 16 + (lane & 15);
        sw_store1(Ys, row, 256, col, f2us(fmaxf(acc[mi][ni][q], 0.f)));
      }
  __syncthreads();

#pragma unroll
  for (int ni = 0; ni < 4; ++ni) {
    const float bv = b3[wn * 64 + ni * 16 + (lane & 15)];
#pragma unroll
    for (int mi = 0; mi < 4; ++mi) acc[mi][ni] = {bv, bv, bv, bv};
  }
#pragma unroll
  for (int kb = 0; kb < 4; ++kb) {
    short8 A[4], Bf[4];
#pragma unroll
    for (int mi = 0; mi < 4; ++mi)
      A[mi] = sw_load8(Ys, wm * 64 + mi * 16 + (lane & 15), 256, kb * 64 + (lane >> 4) * 16);
#pragma unroll
    for (int ni = 0; ni < 4; ++ni)
      Bf[ni] = *(const short8*)&W3f[(((size_t)kb * 8 + wn * 4 + ni) * 64 + lane) * 8];
#pragma unroll
    for (int mi = 0; mi < 4; ++mi)
#pragma unroll
      for (int ni = 0; ni < 4; ++ni)
        acc[mi][ni] = __builtin_amdgcn_mfma_f32_16x16x32_bf16(A[mi], Bf[ni], acc[mi][ni], 0, 0, 0);
  }

  float wrow[4][4];
#pragma unroll
  for (int mi = 0; mi < 4; ++mi)
#pragma unroll
    for (int q = 0; q < 4; ++q)
      wrow[mi][q] = s_watt[wm * 64 + mi * 16 + (lane >> 4) * 4 + q];
#pragma unroll
  for (int ni = 0; ni < 4; ++ni) {
    float p0 = 0.f, p1 = 0.f;
#pragma unroll
    for (int q = 0; q < 4; ++q) {
      p0 += wrow[0][q] * acc[0][ni][q] + wrow[1][q] * acc[1][ni][q];
      p1 += wrow[2][q] * acc[2][ni][q] + wrow[3][q] * acc[3][ni][q];
    }
    p0 += __shfl_xor(p0, 16, 64); p0 += __shfl_xor(p0, 32, 64);
    p1 += __shfl_xor(p1, 16, 64); p1 += __shfl_xor(p1, 32, 64);
    if (lane < 16) {
      dhs[wm * 2 + 0][wn * 64 + ni * 16 + lane] = p0;
      dhs[wm * 2 + 1][wn * 64 + ni * 16 + lane] = p1;
    }
  }
  __syncthreads();

  {
    const int r = node0 + wid;
    const float x0 = hV_in[(size_t)r * HH + lane] + dhs[wid][lane] * (1.f / 30.f);
    const float x1 = hV_in[(size_t)r * HH + lane + 64] + dhs[wid][lane + 64] * (1.f / 30.f);
    float sm = x0 + x1;
#pragma unroll
    for (int m = 32; m >= 1; m >>= 1) sm += __shfl_xor(sm, m, 64);
    const float mu = sm * (1.f / HH);
    const float d0 = x0 - mu, d1 = x1 - mu;
    float vv = d0 * d0 + d1 * d1;
#pragma unroll
    for (int m = 32; m >= 1; m >>= 1) vv += __shfl_xor(vv, m, 64);
    const float rs = rsqrtf(vv * (1.f / HH) + LEPS);
    h1out[(size_t)r * HH + lane] = f2us(g1[lane] * d0 * rs + bt1[lane]);
    h1out[(size_t)r * HH + lane + 64] = f2us(g1[lane + 64] * d1 * rs + bt1[lane + 64]);
  }
}

// ---------------- FF kernel ----------------
__global__ __launch_bounds__(256) void k_ff(
    const ushort_t* __restrict__ h1, const ushort_t* __restrict__ Winf,
    const ushort_t* __restrict__ Wfff,
    const float* __restrict__ bin, const float* __restrict__ bff,
    const float* __restrict__ g2, const float* __restrict__ bt2,
    const float* __restrict__ mask, float* __restrict__ hV_out)
{
  const int t = threadIdx.x, wid = t >> 6, lane = t & 63;
  const int row0 = blockIdx.x * 64;
  __shared__ alignas(16) ushort_t As[64 * 128];
  __shared__ alignas(16) ushort_t Us[64 * 512];

  {
    const int row = t >> 2, cq = t & 3;
    const short8* p = (const short8*)(h1 + (size_t)(row0 + row) * HH + cq * 32);
#pragma unroll
    for (int i = 0; i < 4; ++i) sw_store8(As, row, 256, cq * 64 + i * 16, p[i]);
  }
  __syncthreads();

  f32x4 ua[4][8];
#pragma unroll
  for (int ni = 0; ni < 8; ++ni) {
    const float bv = bin[wid * 128 + ni * 16 + (lane & 15)];
#pragma unroll
    for (int mi = 0; mi < 4; ++mi) ua[mi][ni] = {bv, bv, bv, bv};
  }
#pragma unroll
  for (int kb = 0; kb < 4; ++kb) {
    short8 A[4], Bf[8];
#pragma unroll
    for (int mi = 0; mi < 4; ++mi)
      A[mi] = sw_load8(As, mi * 16 + (lane & 15), 256, kb * 64 + (lane >> 4) * 16);
#pragma unroll
    for (int ni = 0; ni < 8; ++ni)
      Bf[ni] = *(const short8*)&Winf[(((size_t)kb * 32 + wid * 8 + ni) * 64 + lane) * 8];
#pragma unroll
    for (int mi = 0; mi < 4; ++mi)
#pragma unroll
      for (int ni = 0; ni < 8; ++ni)
        ua[mi][ni] = __builtin_amdgcn_mfma_f32_16x16x32_bf16(A[mi], Bf[ni], ua[mi][ni], 0, 0, 0);
  }
#pragma unroll
  for (int mi = 0; mi < 4; ++mi)
#pragma unroll
    for (int ni = 0; ni < 8; ++ni)
#pragma unroll
      for (int q = 0; q < 4; ++q) {
        const int row = mi * 16 + (lane >> 4) * 4 + q;
        const int col = wid * 128 + ni * 16 + (lane & 15);
        sw_store1(Us, row, 1024, col, f2us(fmaxf(ua[mi][ni][q], 0.f)));
      }
  __syncthreads();

  f32x4 fa[4][2];
#pragma unroll
  for (int ni = 0; ni < 2; ++ni) {
    const float bv = bff[wid * 32 + ni * 16 + (lane & 15)];
#pragma unroll
    for (int mi = 0; mi < 4; ++mi) fa[mi][ni] = {bv, bv, bv, bv};
  }
#pragma unroll
  for (int kb = 0; kb < 16; ++kb) {
    short8 A[4], Bf[2];
#pragma unroll
    for (int mi = 0; mi < 4; ++mi)
      A[mi] = sw_load8(Us, mi * 16 + (lane & 15), 1024, kb * 64 + (lane >> 4) * 16);
#pragma unroll
    for (int ni = 0; ni < 2; ++ni)
      Bf[ni] = *(const short8*)&Wfff[(((size_t)kb * 8 + wid * 2 + ni) * 64 + lane) * 8];
#pragma unroll
    for (int mi = 0; mi < 4; ++mi)
#pragma unroll
      for (int ni = 0; ni < 2; ++ni)
        fa[mi][ni] = __builtin_amdgcn_mfma_f32_16x16x32_bf16(A[mi], Bf[ni], fa[mi][ni], 0, 0, 0);
  }
  __syncthreads();

  float* h2 = (float*)Us;
#pragma unroll
  for (int mi = 0; mi < 4; ++mi)
#pragma unroll
    for (int ni = 0; ni < 2; ++ni)
#pragma unroll
      for (int q = 0; q < 4; ++q) {
        const int row = mi * 16 + (lane >> 4) * 4 + q;
        const int col = wid * 32 + ni * 16 + (lane & 15);
        const float res = us2f(h1[(size_t)(row0 + row) * HH + col]);
        h2[row * HH + col] = res + fa[mi][ni][q];
      }
  __syncthreads();

  {
    const int row = t >> 2, quad = t & 3;
    float x[32];
    float sm = 0.f;
#pragma unroll
    for (int i = 0; i < 32; ++i) { x[i] = h2[row * HH + quad + i * 4]; sm += x[i]; }
    sm += __shfl_xor(sm, 1, 64); sm += __shfl_xor(sm, 2, 64);
    const float mu = sm * (1.f / HH);
    float vv = 0.f;
#pragma unroll
    for (int i = 0; i < 32; ++i) { const float d = x[i] - mu; vv += d * d; }
    vv += __shfl_xor(vv, 1, 64); vv += __shfl_xor(vv, 2, 64);
    const float rs = rsqrtf(vv * (1.f / HH) + LEPS);
    const float m1 = mask[row0 + row];
#pragma unroll
    for (int i = 0; i < 32; ++i) {
      const int col = quad + i * 4;
      hV_out[(size_t)(row0 + row) * HH + col] = (g2[col] * (x[i] - mu) * rs + bt2[col]) * m1;
    }
  }
}

// ---------------- logits + log_softmax ----------------
__global__ __launch_bounds__(64) void k_out(
    const float* __restrict__ hV, const float* __restrict__ Wout,
    const float* __restrict__ bout, float* __restrict__ out)
{
  const int r = blockIdx.x;
  const int lane = threadIdx.x;
  __shared__ alignas(16) float sx[HH];
  sx[lane] = hV[(size_t)r * HH + lane];
  sx[lane + 64] = hV[(size_t)r * HH + lane + 64];
  __syncthreads();
  float logit = -1e30f;
  if (lane < NV) {
    float acc = bout[lane];
    for (int i = 0; i < HH; ++i) acc += sx[i] * Wout[i * NV + lane];
    logit = acc;
  }
  float mx = logit;
#pragma unroll
  for (int m = 32; m >= 1; m >>= 1) mx = fmaxf(mx, __shfl_xor(mx, m, 64));
  float e = (lane < NV) ? expf(logit - mx) : 0.f;
  float s = e;
#pragma unroll
  for (int m = 32; m >= 1; m >>= 1) s += __shfl_xor(s, m, 64);
  if (lane < NV) out[(size_t)r * NV + lane] = logit - mx - logf(s);
}

// ---------------- launcher ----------------
extern "C" void kernel_launch(void* const* d_in, const int* in_sizes, int n_in,
                              void* d_out, int out_size, void* d_ws, size_t ws_size,
                              hipStream_t stream)
{
  const int* S = (const int*)d_in[0];
  const float* V = (const float*)d_in[1];
  const float* E = (const float*)d_in[2];
  const int* E_idx = (const int*)d_in[3];
  const float* mask = (const float*)d_in[4];
  const float* Wv = (const float*)d_in[5];
  const float* bv = (const float*)d_in[6];
  const float* We = (const float*)d_in[7];
  const float* be = (const float*)d_in[8];
  const float* Wse = (const float*)d_in[9];
  const float* Wout = (const float*)d_in[10];
  const float* bout = (const float*)d_in[11];
  const float* eW[14];
  const float* dW[14];
  for (int i = 0; i < 14; ++i) eW[i] = (const float*)d_in[12 + i];
  for (int i = 0; i < 14; ++i) dW[i] = (const float*)d_in[26 + i];

  // ws layout (bytes):
  //   hE  bf16 : 62,914,560 @ 0
  //   hVa f32  :  4,194,304 @ 62,914,560
  //   hVb f32  :  4,194,304 @ 67,108,864
  //   h1  bf16 :  2,097,152 @ 71,303,168
  //   hS  bf16 :  2,097,152 @ 73,400,320
  //   WP  bf16 :  2,719,744 @ 75,497,472   (end 78,217,216)
  char* w = (char*)d_ws;
  ushort_t* hE = (ushort_t*)w;
  float* hVa = (float*)(w + 62914560u);
  float* hVb = (float*)(w + 67108864u);
  ushort_t* h1 = (ushort_t*)(w + 71303168u);
  ushort_t* hS = (ushort_t*)(w + 73400320u);
  ushort_t* WP = (ushort_t*)(w + 75497472u);

  const int R = 8 * NN;  // 8192

  // ---- build merged prep table (32 tensors) ----
  PrepTab tab;
  int ti = 0, blk = 0;
  auto addT = [&](const float* src, unsigned dstOff, int K, int nshift) {
    tab.src[ti] = src; tab.dstOff[ti] = dstOff;
    tab.blk0[ti] = blk; tab.nshift[ti] = nshift;
    blk += (K << nshift) >> 8;
    ++ti;
  };
  for (int l = 0; l < 3; ++l) {
    const unsigned base = l * 212992u;
    addT(eW[0] + l * 384 * 128, base + 0,      384, 7);
    addT(eW[2] + l * 128 * 128, base + 49152,  128, 7);
    addT(eW[4] + l * 128 * 128, base + 65536,  128, 7);
    addT(eW[6] + l * 128 * 512, base + 81920,  128, 9);
    addT(eW[8] + l * 512 * 128, base + 147456, 512, 7);
  }
  for (int l = 0; l < 3; ++l) {
    const unsigned base = 638976u + l * 229376u;
    addT(dW[0] + l * 512 * 128, base + 0,      512, 7);
    addT(dW[2] + l * 128 * 128, base + 65536,  128, 7);
    addT(dW[4] + l * 128 * 128, base + 81920,  128, 7);
    addT(dW[6] + l * 128 * 512, base + 98304,  128, 9);
    addT(dW[8] + l * 512 * 128, base + 163840, 512, 7);
  }
  addT(We, 1327104u, 128, 7);
  addT(Wv, 1343488u, 128, 7);
  k_prep_all<<<blk, 256, 0, stream>>>(tab, WP);  // blk == 5312

  // ---- embeddings ----
  k_gemm128<0><<<R / 128, 256, 0, stream>>>(V, WP + 1343488, bv, hVa);        // h_V
  k_hs<<<R * 32 / 256, 256, 0, stream>>>(S, Wse, hS);                          // h_S
  k_gemm128<1><<<R * KNBR / 128, 256, 0, stream>>>(E, WP + 1327104, be, hE);  // h_E

  // encoder (in-place on hVa: msg reads hVa fully before ff overwrites it)
  for (int l = 0; l < 3; ++l) {
    const ushort_t* base = WP + l * 212992;
    k_msg<0><<<2048, 256, 0, stream>>>(hVa, hVa, hS, hE,
        base, base + 49152, base + 65536,
        eW[1] + l * 128, eW[3] + l * 128, eW[5] + l * 128,
        eW[10] + l * 128, eW[11] + l * 128, E_idx, mask, h1);
    k_ff<<<128, 256, 0, stream>>>(h1, base + 81920, base + 147456,
        eW[7] + l * 512, eW[9] + l * 128, eW[12] + l * 128, eW[13] + l * 128,
        mask, hVa);
  }
  // decoder: hV_enc = hVa (preserved); state rotates into hVb
  for (int l = 0; l < 3; ++l) {
    const ushort_t* base = WP + 638976 + l * 229376;
    const float* hin = (l == 0) ? hVa : hVb;
    k_msg<1><<<2048, 256, 0, stream>>>(hin, hVa, hS, hE,
        base, base + 65536, base + 81920,
        dW[1] + l * 128, dW[3] + l * 128, dW[5] + l * 128,
        dW[10] + l * 128, dW[11] + l * 128, E_idx, mask, h1);
    k_ff<<<128, 256, 0, stream>>>(h1, base + 98304, base + 163840,
        dW[7] + l * 512, dW[9] + l * 128, dW[12] + l * 128, dW[13] + l * 128,
        mask, hVb);
  }

  k_out<<<R, 64, 0, stream>>>(hVb, Wout, bout, (float*)d_out);

  (void)in_sizes; (void)n_in; (void)out_size; (void)ws_size;
}